// Round 1
// 174.459 us; speedup vs baseline: 1.0545x; 1.0545x over previous
//
#include <hip/hip_runtime.h>
#include <hip/hip_bf16.h>

#define NUM_B 8
#define SEQ 1024
#define DIM 768
#define NH 12
#define DH 64

typedef __attribute__((ext_vector_type(8))) short bf16x8;
typedef __attribute__((ext_vector_type(4))) float floatx4;
typedef __attribute__((ext_vector_type(4))) unsigned short ushortx4;
typedef __attribute__((ext_vector_type(8))) unsigned short ushortx8;

__device__ __forceinline__ unsigned short f2bf(float f) {
  unsigned u = __float_as_uint(f);
  u += 0x7FFFu + ((u >> 16) & 1u);   // round-to-nearest-even
  return (unsigned short)(u >> 16);
}

// async global->LDS, 16B per lane; LDS dest = wave-uniform base + lane*16
#define GLOAD16(g, l) __builtin_amdgcn_global_load_lds( \
    (const __attribute__((address_space(1))) unsigned int*)(g), \
    (__attribute__((address_space(3))) unsigned int*)(l), 16, 0, 0)

// ---------------- one-shot fp32 -> bf16 conversion (x, Wk, Wo) -------------
__global__ __launch_bounds__(256) void convert_kernel(
    const float* __restrict__ x, const float* __restrict__ Wk,
    const float* __restrict__ Wo, unsigned short* __restrict__ xb,
    unsigned short* __restrict__ Wkb, unsigned short* __restrict__ Wob)
{
  const int NX4 = (8192 * 768) / 4;
  const int NW4 = (768 * 768) / 4;
  int i = blockIdx.x * 256 + threadIdx.x;
  const float* s; unsigned short* d; int off;
  if (i < NX4)            { s = x;  d = xb;  off = i; }
  else if (i < NX4 + NW4) { s = Wk; d = Wkb; off = i - NX4; }
  else                    { s = Wo; d = Wob; off = i - NX4 - NW4; }
  float4 v = ((const float4*)s)[off];
  ushortx4 h;
  h.x = f2bf(v.x); h.y = f2bf(v.y); h.z = f2bf(v.z); h.w = f2bf(v.w);
  ((ushortx4*)d)[off] = h;
}

// ---------------- K projection + fused transpose ---------------------------
// 64(M) x 128(N), BK=64, dbuf swizzled global_load_lds, grid 768 (3/CU).
__global__ __launch_bounds__(256) void proj_k_kernel(
    const unsigned short* __restrict__ xb, const unsigned short* __restrict__ Wkb,
    const float* __restrict__ bk, unsigned short* __restrict__ Kbh,
    unsigned short* __restrict__ KbhT)
{
  __shared__ __align__(16) unsigned short smem[24576];   // 48 KB (2 x 24 KB)
  const int tid = threadIdx.x;
  const int lane = tid & 63;
  const int w = tid >> 6;
  const int wr = w >> 1, wc = w & 1;
  const int quad = lane >> 4, r16 = lane & 15;
  const int rs = r16 & 7;
  const int m0 = blockIdx.x * 64, n0 = blockIdx.y * 128;
  const int wbase = (tid & ~63);

  floatx4 acc[2][4] = {};

  auto stage = [&](int kt, int buf) {
    unsigned short* As = smem + buf * 12288;
    unsigned short* Bs = As + 4096;
#pragma unroll
    for (int i = 0; i < 2; ++i) {
      int c = tid + i * 256;
      int row = c >> 3, g = (c & 7) ^ (row & 7);
      GLOAD16(xb + (size_t)(m0 + row) * DIM + kt + g * 8,
              As + (size_t)(wbase + i * 256) * 8);
    }
#pragma unroll
    for (int i = 0; i < 4; ++i) {
      int c = tid + i * 256;
      int row = c >> 3, g = (c & 7) ^ (row & 7);
      GLOAD16(Wkb + (size_t)(n0 + row) * DIM + kt + g * 8,
              Bs + (size_t)(wbase + i * 256) * 8);
    }
  };

  stage(0, 0);
  int buf = 0;
  for (int it = 0; it < 12; ++it) {
    __syncthreads();
    if (it + 1 < 12) stage((it + 1) * 64, buf ^ 1);
    const unsigned short* As = smem + buf * 12288;
    const unsigned short* Bs = As + 4096;
    bf16x8 af[2][2], bfm[4][2];
#pragma unroll
    for (int mi = 0; mi < 2; ++mi)
#pragma unroll
      for (int kc = 0; kc < 2; ++kc)
        af[mi][kc] = *(const bf16x8*)&As[(wr * 32 + mi * 16 + r16) * 64 + ((kc * 4 + quad) ^ rs) * 8];
#pragma unroll
    for (int ni = 0; ni < 4; ++ni)
#pragma unroll
      for (int kc = 0; kc < 2; ++kc)
        bfm[ni][kc] = *(const bf16x8*)&Bs[(wc * 64 + ni * 16 + r16) * 64 + ((kc * 4 + quad) ^ rs) * 8];
#pragma unroll
    for (int mi = 0; mi < 2; ++mi)
#pragma unroll
      for (int ni = 0; ni < 4; ++ni) {
        acc[mi][ni] = __builtin_amdgcn_mfma_f32_16x16x32_bf16(af[mi][0], bfm[ni][0], acc[mi][ni], 0, 0, 0);
        acc[mi][ni] = __builtin_amdgcn_mfma_f32_16x16x32_bf16(af[mi][1], bfm[ni][1], acc[mi][ni], 0, 0, 0);
      }
    buf ^= 1;
  }

  __syncthreads();                       // reuse smem as Ct [128 n][72]
  unsigned short* Ct = smem;
  const int bb = m0 >> 10, l0 = m0 & 1023;
#pragma unroll
  for (int mi = 0; mi < 2; ++mi)
#pragma unroll
    for (int ni = 0; ni < 4; ++ni) {
      int col = n0 + wc * 64 + ni * 16 + r16;   // j = h*64+dh
      float bias = bk[col];
      int hh = col >> 6, dd = col & 63;
      ushortx4 pk;
#pragma unroll
      for (int r = 0; r < 4; ++r) {
        int mrow = wr * 32 + mi * 16 + quad * 4 + r;
        unsigned short us = f2bf(acc[mi][ni][r] + bias);
        Kbh[((size_t)(bb * NH + hh) * SEQ + l0 + mrow) * DH + dd] = us;
        pk[r] = us;
      }
      *(ushortx4*)&Ct[(wc * 64 + ni * 16 + r16) * 72 + wr * 32 + mi * 16 + quad * 4] = pk;
    }
  __syncthreads();
#pragma unroll
  for (int i = 0; i < 4; ++i) {
    int c = tid + i * 256;
    int row = c >> 3, ch = c & 7;
    ushortx8 v = *(const ushortx8*)&Ct[row * 72 + ch * 8];
    int j = n0 + row;
    int hh = j >> 6, dd = j & 63;
    *(ushortx8*)&KbhT[((size_t)(bb * NH + hh) * DH + dd) * SEQ + l0 + ch * 8] = v;
  }
}

// ---------------- fused attention ------------------------------------------
// grid (qt=8, bh=96), 512 threads. 128 q-rows/block, 8 waves x 16 q.
// Same schedule/layouts as the 4-wave version, but per-wave work halved:
// 3 blocks/CU (LDS-limited) x 8 waves = 24 waves/CU (was 12) for latency
// hiding. S computed TRANSPOSED (St = K*Q^T): C-layout gives each lane 4
// consecutive keys -> P written as 4 ds_write_b64 per lane per tile.
__global__ __launch_bounds__(512) void attn_kernel(
    const unsigned short* __restrict__ Kbh, const unsigned short* __restrict__ KbhT,
    const int* __restrict__ mask, unsigned short* __restrict__ wV)
{
  __shared__ __align__(16) unsigned short smem[25344];   // 49.5 KB
  // [0,16384): Ks/KTs dbuf; [16384, 25088): Ps [128][68]; [25088,): rsum f32[128]
  unsigned short* Ps = smem + 16384;
  float* rsum = (float*)&smem[25088];

  const int tid = threadIdx.x;
  const int lane = tid & 63;
  const int w = tid >> 6;                // 0..7
  const int quad = lane >> 4, r16 = lane & 15;
  const int rs = r16 & 7;
  const int qt = blockIdx.x, bh = blockIdx.y;
  const int b = bh / NH, h = bh % NH;
  const unsigned short* Kb  = Kbh  + (size_t)bh * SEQ * DH;
  const unsigned short* KbT = KbhT + (size_t)bh * DH * SEQ;
  const int q0 = qt * 128;
  const int qw = w * 16;                 // wave's 16-q range within tile
  const int wbase = (tid & ~63);
  // 1/sqrt(768) * log2(e): exp(x*s) == exp2(x*s*log2e), one v_mul saved
  const float SCALE2 = 0.036084391824351615f * 1.4426950408889634f;

  // Q fragments; B-operand layout == A-operand layout per-lane.
  bf16x8 aq[2];
#pragma unroll
  for (int kc = 0; kc < 2; ++kc)
    aq[kc] = *(const bf16x8*)(Kb + (size_t)(q0 + qw + r16) * DH + kc * 32 + quad * 8);

  // mask folded into scale: masked row -> arg 0 -> p=1 (uniform softmax)
  const float scm = (mask[b * SEQ + q0 + qw + r16] != 0) ? SCALE2 : 0.0f;

  floatx4 accO[4] = {};
  float psum = 0.0f;

  auto stage = [&](int kt, int buf) {
    unsigned short* Ks  = smem + buf * 4096;
    unsigned short* KTs = smem + 8192 + buf * 4096;
    // 512 threads x 16B = one 64x64 bf16 tile each, single pass
    int row = tid >> 3, g = (tid & 7) ^ (row & 7);
    GLOAD16(Kb + (size_t)(kt + row) * DH + g * 8,
            Ks + (size_t)wbase * 8);
    GLOAD16(KbT + (size_t)row * SEQ + kt + g * 8,
            KTs + (size_t)wbase * 8);
  };

  stage(0, 0);
  int buf = 0;
  for (int it = 0; it < SEQ / 64; ++it) {
    __syncthreads();
    if (it + 1 < SEQ / 64) stage((it + 1) * 64, buf ^ 1);
    const unsigned short* Ks  = smem + buf * 4096;
    const unsigned short* KTs = smem + 8192 + buf * 4096;

    // St[key][q] = K Q^T ; A = K-frag (m=key), B = aq (n=q)
    floatx4 St[4] = {};
#pragma unroll
    for (int kt = 0; kt < 4; ++kt) {
      int rb = (kt * 16 + r16) * 64;
      bf16x8 k0 = *(const bf16x8*)&Ks[rb + ((quad) ^ rs) * 8];
      bf16x8 k1 = *(const bf16x8*)&Ks[rb + ((4 + quad) ^ rs) * 8];
      St[kt] = __builtin_amdgcn_mfma_f32_16x16x32_bf16(k0, aq[0], St[kt], 0, 0, 0);
      St[kt] = __builtin_amdgcn_mfma_f32_16x16x32_bf16(k1, aq[1], St[kt], 0, 0, 0);
    }

    // P: lane holds keys kt*16+quad*4+{0..3} for q = qw+r16
    // -> exp2, packed cvt, ONE b64 LDS write per kt
    {
      int prow = (qw + r16) * 68 + quad * 4;
#pragma unroll
      for (int kt = 0; kt < 4; ++kt) {
        float p0 = __builtin_amdgcn_exp2f(St[kt][0] * scm);
        float p1 = __builtin_amdgcn_exp2f(St[kt][1] * scm);
        float p2 = __builtin_amdgcn_exp2f(St[kt][2] * scm);
        float p3 = __builtin_amdgcn_exp2f(St[kt][3] * scm);
        psum += (p0 + p1) + (p2 + p3);
        __hip_bfloat162 lo = __float22bfloat162_rn(make_float2(p0, p1));
        __hip_bfloat162 hi = __float22bfloat162_rn(make_float2(p2, p3));
        unsigned u0, u1;
        __builtin_memcpy(&u0, &lo, 4);
        __builtin_memcpy(&u1, &hi, 4);
        *(uint2*)&Ps[prow + kt * 16] = make_uint2(u0, u1);
      }
    }

    // O += P V (same-wave LDS RAW on Ps; V^T tile from KTs)
    bf16x8 ap[2];
#pragma unroll
    for (int kc = 0; kc < 2; ++kc)
      ap[kc] = *(const bf16x8*)&Ps[(qw + r16) * 68 + kc * 32 + quad * 8];
#pragma unroll
    for (int ni = 0; ni < 4; ++ni) {
      int rb = (ni * 16 + r16) * 64;
      bf16x8 v0 = *(const bf16x8*)&KTs[rb + ((quad) ^ rs) * 8];
      bf16x8 v1 = *(const bf16x8*)&KTs[rb + ((4 + quad) ^ rs) * 8];
      accO[ni] = __builtin_amdgcn_mfma_f32_16x16x32_bf16(ap[0], v0, accO[ni], 0, 0, 0);
      accO[ni] = __builtin_amdgcn_mfma_f32_16x16x32_bf16(ap[1], v1, accO[ni], 0, 0, 0);
    }
    buf ^= 1;
  }

  // psum lives at q = qw+r16 (quad-partial): reduce over quads, then
  // LDS hop to re-align with the O epilogue's q = quad*4+r layout.
  {
    float s = psum;
    s += __shfl_xor(s, 16);
    s += __shfl_xor(s, 32);
    if (quad == 0) rsum[qw + r16] = s;
  }
  // same-wave DS in-order: reads below see the writes above (own q-range only)
  float rinv[4];
#pragma unroll
  for (int r = 0; r < 4; ++r)
    rinv[r] = 1.0f / rsum[qw + quad * 4 + r];

#pragma unroll
  for (int ni = 0; ni < 4; ++ni)
#pragma unroll
    for (int r = 0; r < 4; ++r) {
      int l = q0 + qw + quad * 4 + r;
      int col = h * DH + ni * 16 + r16;
      wV[(size_t)(b * SEQ + l) * DIM + col] = f2bf(accO[ni][r] * rinv[r]);
    }
}

// ---------------- output projection: out = wV @ Wo^T + bo (fp32) -----------
__global__ __launch_bounds__(256) void proj_o_kernel(
    const unsigned short* __restrict__ wVb, const unsigned short* __restrict__ Wob,
    const float* __restrict__ bo, float* __restrict__ out)
{
  __shared__ __align__(16) unsigned short smem[24576];   // 48 KB
  const int tid = threadIdx.x;
  const int lane = tid & 63;
  const int w = tid >> 6;
  const int wr = w >> 1, wc = w & 1;
  const int quad = lane >> 4, r16 = lane & 15;
  const int rs = r16 & 7;
  const int m0 = blockIdx.x * 64, n0 = blockIdx.y * 128;
  const int wbase = (tid & ~63);

  floatx4 acc[2][4] = {};

  auto stage = [&](int kt, int buf) {
    unsigned short* As = smem + buf * 12288;
    unsigned short* Bs = As + 4096;
#pragma unroll
    for (int i = 0; i < 2; ++i) {
      int c = tid + i * 256;
      int row = c >> 3, g = (c & 7) ^ (row & 7);
      GLOAD16(wVb + (size_t)(m0 + row) * DIM + kt + g * 8,
              As + (size_t)(wbase + i * 256) * 8);
    }
#pragma unroll
    for (int i = 0; i < 4; ++i) {
      int c = tid + i * 256;
      int row = c >> 3, g = (c & 7) ^ (row & 7);
      GLOAD16(Wob + (size_t)(n0 + row) * DIM + kt + g * 8,
              Bs + (size_t)(wbase + i * 256) * 8);
    }
  };

  stage(0, 0);
  int buf = 0;
  for (int it = 0; it < 12; ++it) {
    __syncthreads();
    if (it + 1 < 12) stage((it + 1) * 64, buf ^ 1);
    const unsigned short* As = smem + buf * 12288;
    const unsigned short* Bs = As + 4096;
    bf16x8 af[2][2], bfm[4][2];
#pragma unroll
    for (int mi = 0; mi < 2; ++mi)
#pragma unroll
      for (int kc = 0; kc < 2; ++kc)
        af[mi][kc] = *(const bf16x8*)&As[(wr * 32 + mi * 16 + r16) * 64 + ((kc * 4 + quad) ^ rs) * 8];
#pragma unroll
    for (int ni = 0; ni < 4; ++ni)
#pragma unroll
      for (int kc = 0; kc < 2; ++kc)
        bfm[ni][kc] = *(const bf16x8*)&Bs[(wc * 64 + ni * 16 + r16) * 64 + ((kc * 4 + quad) ^ rs) * 8];
#pragma unroll
    for (int mi = 0; mi < 2; ++mi)
#pragma unroll
      for (int ni = 0; ni < 4; ++ni) {
        acc[mi][ni] = __builtin_amdgcn_mfma_f32_16x16x32_bf16(af[mi][0], bfm[ni][0], acc[mi][ni], 0, 0, 0);
        acc[mi][ni] = __builtin_amdgcn_mfma_f32_16x16x32_bf16(af[mi][1], bfm[ni][1], acc[mi][ni], 0, 0, 0);
      }
    buf ^= 1;
  }

#pragma unroll
  for (int mi = 0; mi < 2; ++mi)
#pragma unroll
    for (int ni = 0; ni < 4; ++ni) {
      int col = n0 + wc * 64 + ni * 16 + r16;
      float bias = bo[col];
#pragma unroll
      for (int r = 0; r < 4; ++r) {
        int row = m0 + wr * 32 + mi * 16 + quad * 4 + r;
        out[(size_t)row * DIM + col] = acc[mi][ni][r] + bias;
      }
    }
}

extern "C" void kernel_launch(void* const* d_in, const int* in_sizes, int n_in,
                              void* d_out, int out_size, void* d_ws, size_t ws_size,
                              hipStream_t stream) {
  // inputs: x, attention_mask, Wq, bq, Wk, bk, Wv, bv, Wo, bo  (Q dead; V==K)
  const float* x  = (const float*)d_in[0];
  const int* mask = (const int*)d_in[1];
  const float* Wk = (const float*)d_in[4];
  const float* bk = (const float*)d_in[5];
  const float* Wo = (const float*)d_in[8];
  const float* bo = (const float*)d_in[9];
  float* out = (float*)d_out;

  unsigned short* p = (unsigned short*)d_ws;
  unsigned short* xb   = p;  p += (size_t)8192 * 768;
  unsigned short* Wkb  = p;  p += (size_t)768 * 768;
  unsigned short* Wob  = p;  p += (size_t)768 * 768;
  unsigned short* Kbh  = p;  p += (size_t)NUM_B * NH * SEQ * DH;
  unsigned short* KbhT = p;  p += (size_t)NUM_B * NH * SEQ * DH;
  unsigned short* wVb  = p;  // [8192][768]

  convert_kernel<<<7296, 256, 0, stream>>>(x, Wk, Wo, xb, Wkb, Wob);
  proj_k_kernel<<<dim3(128, 6), 256, 0, stream>>>(xb, Wkb, bk, Kbh, KbhT);
  attn_kernel<<<dim3(8, NUM_B * NH), 512, 0, stream>>>(Kbh, KbhT, mask, wVb);
  proj_o_kernel<<<dim3(128, 6), 256, 0, stream>>>(wVb, Wob, bo, out);
}

// Round 2
// 173.358 us; speedup vs baseline: 1.0612x; 1.0063x over previous
//
#include <hip/hip_runtime.h>
#include <hip/hip_bf16.h>

#define NUM_B 8
#define SEQ 1024
#define DIM 768
#define NH 12
#define DH 64

typedef __attribute__((ext_vector_type(8))) short bf16x8;
typedef __attribute__((ext_vector_type(4))) float floatx4;
typedef __attribute__((ext_vector_type(4))) unsigned short ushortx4;
typedef __attribute__((ext_vector_type(8))) unsigned short ushortx8;

__device__ __forceinline__ unsigned short f2bf(float f) {
  unsigned u = __float_as_uint(f);
  u += 0x7FFFu + ((u >> 16) & 1u);   // round-to-nearest-even
  return (unsigned short)(u >> 16);
}

// async global->LDS, 16B per lane; LDS dest = wave-uniform base + lane*16
#define GLOAD16(g, l) __builtin_amdgcn_global_load_lds( \
    (const __attribute__((address_space(1))) unsigned int*)(g), \
    (__attribute__((address_space(3))) unsigned int*)(l), 16, 0, 0)

// ---------------- one-shot fp32 -> bf16 conversion (x, Wk, Wo) -------------
__global__ __launch_bounds__(256) void convert_kernel(
    const float* __restrict__ x, const float* __restrict__ Wk,
    const float* __restrict__ Wo, unsigned short* __restrict__ xb,
    unsigned short* __restrict__ Wkb, unsigned short* __restrict__ Wob)
{
  const int NX4 = (8192 * 768) / 4;
  const int NW4 = (768 * 768) / 4;
  int i = blockIdx.x * 256 + threadIdx.x;
  const float* s; unsigned short* d; int off;
  if (i < NX4)            { s = x;  d = xb;  off = i; }
  else if (i < NX4 + NW4) { s = Wk; d = Wkb; off = i - NX4; }
  else                    { s = Wo; d = Wob; off = i - NX4 - NW4; }
  float4 v = ((const float4*)s)[off];
  ushortx4 h;
  h.x = f2bf(v.x); h.y = f2bf(v.y); h.z = f2bf(v.z); h.w = f2bf(v.w);
  ((ushortx4*)d)[off] = h;
}

// ---------------- K projection + fused transpose ---------------------------
// 64(M) x 128(N), BK=64, dbuf swizzled global_load_lds, grid 768 (3/CU).
__global__ __launch_bounds__(256) void proj_k_kernel(
    const unsigned short* __restrict__ xb, const unsigned short* __restrict__ Wkb,
    const float* __restrict__ bk, unsigned short* __restrict__ Kbh,
    unsigned short* __restrict__ KbhT)
{
  __shared__ __align__(16) unsigned short smem[24576];   // 48 KB (2 x 24 KB)
  const int tid = threadIdx.x;
  const int lane = tid & 63;
  const int w = tid >> 6;
  const int wr = w >> 1, wc = w & 1;
  const int quad = lane >> 4, r16 = lane & 15;
  const int rs = r16 & 7;
  const int m0 = blockIdx.x * 64, n0 = blockIdx.y * 128;
  const int wbase = (tid & ~63);

  floatx4 acc[2][4] = {};

  auto stage = [&](int kt, int buf) {
    unsigned short* As = smem + buf * 12288;
    unsigned short* Bs = As + 4096;
#pragma unroll
    for (int i = 0; i < 2; ++i) {
      int c = tid + i * 256;
      int row = c >> 3, g = (c & 7) ^ (row & 7);
      GLOAD16(xb + (size_t)(m0 + row) * DIM + kt + g * 8,
              As + (size_t)(wbase + i * 256) * 8);
    }
#pragma unroll
    for (int i = 0; i < 4; ++i) {
      int c = tid + i * 256;
      int row = c >> 3, g = (c & 7) ^ (row & 7);
      GLOAD16(Wkb + (size_t)(n0 + row) * DIM + kt + g * 8,
              Bs + (size_t)(wbase + i * 256) * 8);
    }
  };

  stage(0, 0);
  int buf = 0;
  for (int it = 0; it < 12; ++it) {
    __syncthreads();
    if (it + 1 < 12) stage((it + 1) * 64, buf ^ 1);
    const unsigned short* As = smem + buf * 12288;
    const unsigned short* Bs = As + 4096;
    bf16x8 af[2][2], bfm[4][2];
#pragma unroll
    for (int mi = 0; mi < 2; ++mi)
#pragma unroll
      for (int kc = 0; kc < 2; ++kc)
        af[mi][kc] = *(const bf16x8*)&As[(wr * 32 + mi * 16 + r16) * 64 + ((kc * 4 + quad) ^ rs) * 8];
#pragma unroll
    for (int ni = 0; ni < 4; ++ni)
#pragma unroll
      for (int kc = 0; kc < 2; ++kc)
        bfm[ni][kc] = *(const bf16x8*)&Bs[(wc * 64 + ni * 16 + r16) * 64 + ((kc * 4 + quad) ^ rs) * 8];
#pragma unroll
    for (int mi = 0; mi < 2; ++mi)
#pragma unroll
      for (int ni = 0; ni < 4; ++ni) {
        acc[mi][ni] = __builtin_amdgcn_mfma_f32_16x16x32_bf16(af[mi][0], bfm[ni][0], acc[mi][ni], 0, 0, 0);
        acc[mi][ni] = __builtin_amdgcn_mfma_f32_16x16x32_bf16(af[mi][1], bfm[ni][1], acc[mi][ni], 0, 0, 0);
      }
    buf ^= 1;
  }

  __syncthreads();                       // reuse smem as Ct [128 n][72]
  unsigned short* Ct = smem;
  const int bb = m0 >> 10, l0 = m0 & 1023;
#pragma unroll
  for (int mi = 0; mi < 2; ++mi)
#pragma unroll
    for (int ni = 0; ni < 4; ++ni) {
      int col = n0 + wc * 64 + ni * 16 + r16;   // j = h*64+dh
      float bias = bk[col];
      int hh = col >> 6, dd = col & 63;
      ushortx4 pk;
#pragma unroll
      for (int r = 0; r < 4; ++r) {
        int mrow = wr * 32 + mi * 16 + quad * 4 + r;
        unsigned short us = f2bf(acc[mi][ni][r] + bias);
        Kbh[((size_t)(bb * NH + hh) * SEQ + l0 + mrow) * DH + dd] = us;
        pk[r] = us;
      }
      *(ushortx4*)&Ct[(wc * 64 + ni * 16 + r16) * 72 + wr * 32 + mi * 16 + quad * 4] = pk;
    }
  __syncthreads();
#pragma unroll
  for (int i = 0; i < 4; ++i) {
    int c = tid + i * 256;
    int row = c >> 3, ch = c & 7;
    ushortx8 v = *(const ushortx8*)&Ct[row * 72 + ch * 8];
    int j = n0 + row;
    int hh = j >> 6, dd = j & 63;
    *(ushortx8*)&KbhT[((size_t)(bb * NH + hh) * DH + dd) * SEQ + l0 + ch * 8] = v;
  }
}

// ---------------- fused attention ------------------------------------------
// 1-D grid 768, 512 threads. 128 q-rows/block, 8 waves x 16 q.
// XCD-aware decode: the 8 q-tiles sharing one bh's K/KT all land on the SAME
// XCD (linear%8 == bh%8), so K/KT are fetched from HBM once per bh and served
// from that XCD's L2 thereafter (12 bh x 256 KB = 3 MB < 4 MB L2 per XCD).
// S computed TRANSPOSED (St = K*Q^T): C-layout gives each lane 4 consecutive
// keys -> P written as 4 ds_write_b64 per lane per tile.
__global__ __launch_bounds__(512) void attn_kernel(
    const unsigned short* __restrict__ Kbh, const unsigned short* __restrict__ KbhT,
    const int* __restrict__ mask, unsigned short* __restrict__ wV)
{
  __shared__ __align__(16) unsigned short smem[25344];   // 49.5 KB
  // [0,16384): Ks/KTs dbuf; [16384, 25088): Ps [128][68]; [25088,): rsum f32[128]
  unsigned short* Ps = smem + 16384;
  float* rsum = (float*)&smem[25088];

  const int tid = threadIdx.x;
  const int lane = tid & 63;
  const int w = tid >> 6;                // 0..7
  const int quad = lane >> 4, r16 = lane & 15;
  const int rs = r16 & 7;
  // XCD-aware bijective decode (XCD = linear%8 round-robin assumption):
  const int Lb = blockIdx.x;
  const int qt = (Lb >> 3) & 7;
  const int bh = (Lb >> 6) * 8 + (Lb & 7);
  const int b = bh / NH, h = bh % NH;
  const unsigned short* Kb  = Kbh  + (size_t)bh * SEQ * DH;
  const unsigned short* KbT = KbhT + (size_t)bh * DH * SEQ;
  const int q0 = qt * 128;
  const int qw = w * 16;                 // wave's 16-q range within tile
  const int wbase = (tid & ~63);
  // 1/sqrt(768) * log2(e): exp(x*s) == exp2(x*s*log2e), one v_mul saved
  const float SCALE2 = 0.036084391824351615f * 1.4426950408889634f;

  // Q fragments; B-operand layout == A-operand layout per-lane.
  bf16x8 aq[2];
#pragma unroll
  for (int kc = 0; kc < 2; ++kc)
    aq[kc] = *(const bf16x8*)(Kb + (size_t)(q0 + qw + r16) * DH + kc * 32 + quad * 8);

  // mask folded into scale: masked row -> arg 0 -> p=1 (uniform softmax)
  const float scm = (mask[b * SEQ + q0 + qw + r16] != 0) ? SCALE2 : 0.0f;

  floatx4 accO[4] = {};
  float psum = 0.0f;

  auto stage = [&](int kt, int buf) {
    unsigned short* Ks  = smem + buf * 4096;
    unsigned short* KTs = smem + 8192 + buf * 4096;
    // 512 threads x 16B = one 64x64 bf16 tile each, single pass
    int row = tid >> 3, g = (tid & 7) ^ (row & 7);
    GLOAD16(Kb + (size_t)(kt + row) * DH + g * 8,
            Ks + (size_t)wbase * 8);
    GLOAD16(KbT + (size_t)row * SEQ + kt + g * 8,
            KTs + (size_t)wbase * 8);
  };

  stage(0, 0);
  int buf = 0;
  for (int it = 0; it < SEQ / 64; ++it) {
    __syncthreads();
    if (it + 1 < SEQ / 64) stage((it + 1) * 64, buf ^ 1);
    const unsigned short* Ks  = smem + buf * 4096;
    const unsigned short* KTs = smem + 8192 + buf * 4096;

    // St[key][q] = K Q^T ; A = K-frag (m=key), B = aq (n=q)
    floatx4 St[4] = {};
    __builtin_amdgcn_s_setprio(1);
#pragma unroll
    for (int kt = 0; kt < 4; ++kt) {
      int rb = (kt * 16 + r16) * 64;
      bf16x8 k0 = *(const bf16x8*)&Ks[rb + ((quad) ^ rs) * 8];
      bf16x8 k1 = *(const bf16x8*)&Ks[rb + ((4 + quad) ^ rs) * 8];
      St[kt] = __builtin_amdgcn_mfma_f32_16x16x32_bf16(k0, aq[0], St[kt], 0, 0, 0);
      St[kt] = __builtin_amdgcn_mfma_f32_16x16x32_bf16(k1, aq[1], St[kt], 0, 0, 0);
    }
    __builtin_amdgcn_s_setprio(0);

    // P: lane holds keys kt*16+quad*4+{0..3} for q = qw+r16
    // -> exp2, packed cvt, ONE b64 LDS write per kt
    {
      int prow = (qw + r16) * 68 + quad * 4;
#pragma unroll
      for (int kt = 0; kt < 4; ++kt) {
        float p0 = __builtin_amdgcn_exp2f(St[kt][0] * scm);
        float p1 = __builtin_amdgcn_exp2f(St[kt][1] * scm);
        float p2 = __builtin_amdgcn_exp2f(St[kt][2] * scm);
        float p3 = __builtin_amdgcn_exp2f(St[kt][3] * scm);
        psum += (p0 + p1) + (p2 + p3);
        __hip_bfloat162 lo = __float22bfloat162_rn(make_float2(p0, p1));
        __hip_bfloat162 hi = __float22bfloat162_rn(make_float2(p2, p3));
        unsigned u0, u1;
        __builtin_memcpy(&u0, &lo, 4);
        __builtin_memcpy(&u1, &hi, 4);
        *(uint2*)&Ps[prow + kt * 16] = make_uint2(u0, u1);
      }
    }

    // O += P V (same-wave LDS RAW on Ps; V^T tile from KTs)
    bf16x8 ap[2];
#pragma unroll
    for (int kc = 0; kc < 2; ++kc)
      ap[kc] = *(const bf16x8*)&Ps[(qw + r16) * 68 + kc * 32 + quad * 8];
    __builtin_amdgcn_s_setprio(1);
#pragma unroll
    for (int ni = 0; ni < 4; ++ni) {
      int rb = (ni * 16 + r16) * 64;
      bf16x8 v0 = *(const bf16x8*)&KTs[rb + ((quad) ^ rs) * 8];
      bf16x8 v1 = *(const bf16x8*)&KTs[rb + ((4 + quad) ^ rs) * 8];
      accO[ni] = __builtin_amdgcn_mfma_f32_16x16x32_bf16(ap[0], v0, accO[ni], 0, 0, 0);
      accO[ni] = __builtin_amdgcn_mfma_f32_16x16x32_bf16(ap[1], v1, accO[ni], 0, 0, 0);
    }
    __builtin_amdgcn_s_setprio(0);
    buf ^= 1;
  }

  // psum lives at q = qw+r16 (quad-partial): reduce over quads, then
  // LDS hop to re-align with the O epilogue's q = quad*4+r layout.
  {
    float s = psum;
    s += __shfl_xor(s, 16);
    s += __shfl_xor(s, 32);
    if (quad == 0) rsum[qw + r16] = s;
  }
  // same-wave DS in-order: reads below see the writes above (own q-range only)
  float rinv[4];
#pragma unroll
  for (int r = 0; r < 4; ++r)
    rinv[r] = 1.0f / rsum[qw + quad * 4 + r];

#pragma unroll
  for (int ni = 0; ni < 4; ++ni)
#pragma unroll
    for (int r = 0; r < 4; ++r) {
      int l = q0 + qw + quad * 4 + r;
      int col = h * DH + ni * 16 + r16;
      wV[(size_t)(b * SEQ + l) * DIM + col] = f2bf(accO[ni][r] * rinv[r]);
    }
}

// ---------------- output projection: out = wV @ Wo^T + bo (fp32) -----------
__global__ __launch_bounds__(256) void proj_o_kernel(
    const unsigned short* __restrict__ wVb, const unsigned short* __restrict__ Wob,
    const float* __restrict__ bo, float* __restrict__ out)
{
  __shared__ __align__(16) unsigned short smem[24576];   // 48 KB
  const int tid = threadIdx.x;
  const int lane = tid & 63;
  const int w = tid >> 6;
  const int wr = w >> 1, wc = w & 1;
  const int quad = lane >> 4, r16 = lane & 15;
  const int rs = r16 & 7;
  const int m0 = blockIdx.x * 64, n0 = blockIdx.y * 128;
  const int wbase = (tid & ~63);

  floatx4 acc[2][4] = {};

  auto stage = [&](int kt, int buf) {
    unsigned short* As = smem + buf * 12288;
    unsigned short* Bs = As + 4096;
#pragma unroll
    for (int i = 0; i < 2; ++i) {
      int c = tid + i * 256;
      int row = c >> 3, g = (c & 7) ^ (row & 7);
      GLOAD16(wVb + (size_t)(m0 + row) * DIM + kt + g * 8,
              As + (size_t)(wbase + i * 256) * 8);
    }
#pragma unroll
    for (int i = 0; i < 4; ++i) {
      int c = tid + i * 256;
      int row = c >> 3, g = (c & 7) ^ (row & 7);
      GLOAD16(Wob + (size_t)(n0 + row) * DIM + kt + g * 8,
              Bs + (size_t)(wbase + i * 256) * 8);
    }
  };

  stage(0, 0);
  int buf = 0;
  for (int it = 0; it < 12; ++it) {
    __syncthreads();
    if (it + 1 < 12) stage((it + 1) * 64, buf ^ 1);
    const unsigned short* As = smem + buf * 12288;
    const unsigned short* Bs = As + 4096;
    bf16x8 af[2][2], bfm[4][2];
#pragma unroll
    for (int mi = 0; mi < 2; ++mi)
#pragma unroll
      for (int kc = 0; kc < 2; ++kc)
        af[mi][kc] = *(const bf16x8*)&As[(wr * 32 + mi * 16 + r16) * 64 + ((kc * 4 + quad) ^ rs) * 8];
#pragma unroll
    for (int ni = 0; ni < 4; ++ni)
#pragma unroll
      for (int kc = 0; kc < 2; ++kc)
        bfm[ni][kc] = *(const bf16x8*)&Bs[(wc * 64 + ni * 16 + r16) * 64 + ((kc * 4 + quad) ^ rs) * 8];
#pragma unroll
    for (int mi = 0; mi < 2; ++mi)
#pragma unroll
      for (int ni = 0; ni < 4; ++ni) {
        acc[mi][ni] = __builtin_amdgcn_mfma_f32_16x16x32_bf16(af[mi][0], bfm[ni][0], acc[mi][ni], 0, 0, 0);
        acc[mi][ni] = __builtin_amdgcn_mfma_f32_16x16x32_bf16(af[mi][1], bfm[ni][1], acc[mi][ni], 0, 0, 0);
      }
    buf ^= 1;
  }

#pragma unroll
  for (int mi = 0; mi < 2; ++mi)
#pragma unroll
    for (int ni = 0; ni < 4; ++ni) {
      int col = n0 + wc * 64 + ni * 16 + r16;
      float bias = bo[col];
#pragma unroll
      for (int r = 0; r < 4; ++r) {
        int row = m0 + wr * 32 + mi * 16 + quad * 4 + r;
        out[(size_t)row * DIM + col] = acc[mi][ni][r] + bias;
      }
    }
}

extern "C" void kernel_launch(void* const* d_in, const int* in_sizes, int n_in,
                              void* d_out, int out_size, void* d_ws, size_t ws_size,
                              hipStream_t stream) {
  // inputs: x, attention_mask, Wq, bq, Wk, bk, Wv, bv, Wo, bo  (Q dead; V==K)
  const float* x  = (const float*)d_in[0];
  const int* mask = (const int*)d_in[1];
  const float* Wk = (const float*)d_in[4];
  const float* bk = (const float*)d_in[5];
  const float* Wo = (const float*)d_in[8];
  const float* bo = (const float*)d_in[9];
  float* out = (float*)d_out;

  unsigned short* p = (unsigned short*)d_ws;
  unsigned short* xb   = p;  p += (size_t)8192 * 768;
  unsigned short* Wkb  = p;  p += (size_t)768 * 768;
  unsigned short* Wob  = p;  p += (size_t)768 * 768;
  unsigned short* Kbh  = p;  p += (size_t)NUM_B * NH * SEQ * DH;
  unsigned short* KbhT = p;  p += (size_t)NUM_B * NH * SEQ * DH;
  unsigned short* wVb  = p;  // [8192][768]

  convert_kernel<<<7296, 256, 0, stream>>>(x, Wk, Wo, xb, Wkb, Wob);
  proj_k_kernel<<<dim3(128, 6), 256, 0, stream>>>(xb, Wkb, bk, Kbh, KbhT);
  attn_kernel<<<768, 512, 0, stream>>>(Kbh, KbhT, mask, wVb);
  proj_o_kernel<<<dim3(128, 6), 256, 0, stream>>>(wVb, Wob, bo, out);
}